// Round 4
// baseline (69.383 us; speedup 1.0000x reference)
//
#include <hip/hip_runtime.h>
#include <hip/hip_bf16.h>

typedef __attribute__((ext_vector_type(8))) short s16x8;
typedef __attribute__((ext_vector_type(4))) short s16x4;
typedef __attribute__((ext_vector_type(4))) float fx4;

#define DEVINL __device__ __forceinline__

constexpr int EMBED = 768;
constexpr int HD    = 64;
constexpr int NB    = 16;
constexpr int LEN   = 1024;
constexpr int M_TOT = NB * LEN;  // 16384
constexpr int KVQ   = LEN / 4;   // 256 kv per group in fused attn

// fp32 -> bf16 RNE via v_cvt_pk_bf16_f32 (2 elems/inst).
DEVINL unsigned pk2(float lo, float hi) {
  __hip_bfloat162 h = __float22bfloat162_rn(float2{lo, hi});
  union { __hip_bfloat162 h; unsigned u; } c; c.h = h;
  return c.u;
}
DEVINL s16x8 cvt8(fx4 a, fx4 b) {
  union { unsigned u[4]; s16x8 v; } r;
  r.u[0] = pk2(a[0], a[1]); r.u[1] = pk2(a[2], a[3]);
  r.u[2] = pk2(b[0], b[1]); r.u[3] = pk2(b[2], b[3]);
  return r.v;
}
DEVINL s16x4 cvt4(float a0, float a1, float a2, float a3) {
  union { unsigned u[2]; s16x4 v; } r;
  r.u[0] = pk2(a0, a1); r.u[1] = pk2(a2, a3);
  return r.v;
}

DEVINL fx4 mfma16(s16x8 a, s16x8 b, fx4 c) {
  return __builtin_amdgcn_mfma_f32_16x16x32_bf16(a, b, c, 0, 0, 0);
}

// ---------------------------------------------------------------------------
// proj_q: Y[m][d] = bf16( X[m][:] @ W[d][:] + b[d] ). Block = 1024 threads =
// 16 waves = 4 K-groups x 4 waves; partials summed through LDS.
// ---------------------------------------------------------------------------
__global__ __launch_bounds__(1024, 4) void proj_q_kernel(
    const float* __restrict__ X, const float* __restrict__ W,
    const float* __restrict__ bias, short* __restrict__ Y)
{
  __shared__ short Xs[4][64][40];
  __shared__ short Ws[4][64][40];
  __shared__ float Red[64][68];
  const int t = threadIdx.x, wv = t >> 6, lane = t & 63;
  const int g = wv >> 2, wl = wv & 3, u = t & 255;
  const int fr = lane & 15, fg = lane >> 4;
  const int m0 = blockIdx.x * 64;
  const int srow = u >> 2, scol = (u & 3) * 8;

  const float* xrow = X + (size_t)(m0 + srow) * EMBED + g * 192 + scol;
  const float* wrow = W + (size_t)srow * EMBED + g * 192 + scol;

  fx4 acc[4];
#pragma unroll
  for (int c = 0; c < 4; ++c) acc[c] = fx4{0.f, 0.f, 0.f, 0.f};

  fx4 px0 = *reinterpret_cast<const fx4*>(xrow);
  fx4 px1 = *reinterpret_cast<const fx4*>(xrow + 4);
  fx4 pw0 = *reinterpret_cast<const fx4*>(wrow);
  fx4 pw1 = *reinterpret_cast<const fx4*>(wrow + 4);

#pragma unroll
  for (int s = 0; s < 6; ++s) {
    s16x8 xb = cvt8(px0, px1);
    s16x8 wb = cvt8(pw0, pw1);
    __syncthreads();  // previous step's fragment reads complete
    *reinterpret_cast<s16x8*>(&Xs[g][srow][scol]) = xb;
    *reinterpret_cast<s16x8*>(&Ws[g][srow][scol]) = wb;
    if (s < 5) {  // prefetch next step
      px0 = *reinterpret_cast<const fx4*>(xrow + (s + 1) * 32);
      px1 = *reinterpret_cast<const fx4*>(xrow + (s + 1) * 32 + 4);
      pw0 = *reinterpret_cast<const fx4*>(wrow + (s + 1) * 32);
      pw1 = *reinterpret_cast<const fx4*>(wrow + (s + 1) * 32 + 4);
    }
    __syncthreads();
    s16x8 xa = *reinterpret_cast<const s16x8*>(&Xs[g][wl * 16 + fr][fg * 8]);
#pragma unroll
    for (int c = 0; c < 4; ++c) {
      s16x8 wf = *reinterpret_cast<const s16x8*>(&Ws[g][c * 16 + fr][fg * 8]);
      acc[c] = mfma16(wf, xa, acc[c]);  // D[d][m]: d=c*16+fg*4+r, m=wl*16+fr
    }
  }
  for (int gg = 0; gg < 4; ++gg) {
    if (g == gg) {
#pragma unroll
      for (int c = 0; c < 4; ++c) {
        float* p = &Red[wl * 16 + fr][c * 16 + fg * 4];
        if (gg == 0) {
          *reinterpret_cast<fx4*>(p) = acc[c];
        } else {
          fx4 v = *reinterpret_cast<fx4*>(p);
#pragma unroll
          for (int r = 0; r < 4; ++r) v[r] += acc[c][r];
          *reinterpret_cast<fx4*>(p) = v;
        }
      }
    }
    __syncthreads();
  }
  const int row = t >> 4, d0 = (t & 15) * 4;
  fx4 v = *reinterpret_cast<const fx4*>(&Red[row][d0]);
  fx4 bv = *reinterpret_cast<const fx4*>(bias + d0);
  *reinterpret_cast<s16x4*>(Y + (size_t)(m0 + row) * HD + d0) =
      cvt4(v[0] + bv[0], v[1] + bv[1], v[2] + bv[2], v[3] + bv[3]);
}

// ---------------------------------------------------------------------------
// proj_kv: enc -> K [b,kv,64] bf16 and V^T [b,64,kv] bf16. Same structure.
// ---------------------------------------------------------------------------
__global__ __launch_bounds__(1024, 4) void proj_kv_kernel(
    const float* __restrict__ X,
    const float* __restrict__ Wk, const float* __restrict__ bk,
    const float* __restrict__ Wv, const float* __restrict__ bv,
    short* __restrict__ Kout, short* __restrict__ VT)
{
  __shared__ short Xs[4][64][40];
  __shared__ short Wks[4][64][40];
  __shared__ short Wvs[4][64][40];
  __shared__ float Kred[64][68];
  __shared__ float Vred[64][68];
  const int t = threadIdx.x, wv = t >> 6, lane = t & 63;
  const int g = wv >> 2, wl = wv & 3, u = t & 255;
  const int fr = lane & 15, fg = lane >> 4;
  const int m0 = blockIdx.x * 64;
  const int srow = u >> 2, scol = (u & 3) * 8;

  const float* xrow  = X  + (size_t)(m0 + srow) * EMBED + g * 192 + scol;
  const float* wkrow = Wk + (size_t)srow * EMBED + g * 192 + scol;
  const float* wvrow = Wv + (size_t)srow * EMBED + g * 192 + scol;

  fx4 kacc[4], vacc[4];
#pragma unroll
  for (int c = 0; c < 4; ++c) {
    kacc[c] = fx4{0.f, 0.f, 0.f, 0.f};
    vacc[c] = fx4{0.f, 0.f, 0.f, 0.f};
  }

  fx4 px0 = *reinterpret_cast<const fx4*>(xrow);
  fx4 px1 = *reinterpret_cast<const fx4*>(xrow + 4);
  fx4 pk0 = *reinterpret_cast<const fx4*>(wkrow);
  fx4 pk1 = *reinterpret_cast<const fx4*>(wkrow + 4);
  fx4 pv0 = *reinterpret_cast<const fx4*>(wvrow);
  fx4 pv1 = *reinterpret_cast<const fx4*>(wvrow + 4);

#pragma unroll
  for (int s = 0; s < 6; ++s) {
    s16x8 xb = cvt8(px0, px1);
    s16x8 kb = cvt8(pk0, pk1);
    s16x8 vb = cvt8(pv0, pv1);
    __syncthreads();
    *reinterpret_cast<s16x8*>(&Xs[g][srow][scol])  = xb;
    *reinterpret_cast<s16x8*>(&Wks[g][srow][scol]) = kb;
    *reinterpret_cast<s16x8*>(&Wvs[g][srow][scol]) = vb;
    if (s < 5) {
      px0 = *reinterpret_cast<const fx4*>(xrow + (s + 1) * 32);
      px1 = *reinterpret_cast<const fx4*>(xrow + (s + 1) * 32 + 4);
      pk0 = *reinterpret_cast<const fx4*>(wkrow + (s + 1) * 32);
      pk1 = *reinterpret_cast<const fx4*>(wkrow + (s + 1) * 32 + 4);
      pv0 = *reinterpret_cast<const fx4*>(wvrow + (s + 1) * 32);
      pv1 = *reinterpret_cast<const fx4*>(wvrow + (s + 1) * 32 + 4);
    }
    __syncthreads();
    s16x8 xa = *reinterpret_cast<const s16x8*>(&Xs[g][wl * 16 + fr][fg * 8]);
#pragma unroll
    for (int c = 0; c < 4; ++c) {
      s16x8 wkf = *reinterpret_cast<const s16x8*>(&Wks[g][c * 16 + fr][fg * 8]);
      s16x8 wvf = *reinterpret_cast<const s16x8*>(&Wvs[g][c * 16 + fr][fg * 8]);
      kacc[c] = mfma16(wkf, xa, kacc[c]);
      vacc[c] = mfma16(wvf, xa, vacc[c]);
    }
  }
  for (int gg = 0; gg < 4; ++gg) {
    if (g == gg) {
#pragma unroll
      for (int c = 0; c < 4; ++c) {
        float* pk = &Kred[wl * 16 + fr][c * 16 + fg * 4];
        float* pv = &Vred[wl * 16 + fr][c * 16 + fg * 4];
        if (gg == 0) {
          *reinterpret_cast<fx4*>(pk) = kacc[c];
          *reinterpret_cast<fx4*>(pv) = vacc[c];
        } else {
          fx4 a = *reinterpret_cast<fx4*>(pk);
          fx4 b = *reinterpret_cast<fx4*>(pv);
#pragma unroll
          for (int r = 0; r < 4; ++r) { a[r] += kacc[c][r]; b[r] += vacc[c][r]; }
          *reinterpret_cast<fx4*>(pk) = a;
          *reinterpret_cast<fx4*>(pv) = b;
        }
      }
    }
    __syncthreads();
  }
  {
    const int row = t >> 4, d0 = (t & 15) * 4;
    fx4 v = *reinterpret_cast<const fx4*>(&Kred[row][d0]);
    fx4 b4 = *reinterpret_cast<const fx4*>(bk + d0);
    *reinterpret_cast<s16x4*>(Kout + (size_t)(m0 + row) * HD + d0) =
        cvt4(v[0] + b4[0], v[1] + b4[1], v[2] + b4[2], v[3] + b4[3]);
  }
  {
    const int d = t >> 4, seg = t & 15;
    const int bidx = m0 >> 10;             // 64 | 1024: no batch straddle
    const int kvpos = (m0 & 1023) + seg * 4;
    const float bvd = bv[d];
    *reinterpret_cast<s16x4*>(VT + ((size_t)(bidx * HD + d)) * LEN + kvpos) =
        cvt4(Vred[seg * 4][d] + bvd, Vred[seg * 4 + 1][d] + bvd,
             Vred[seg * 4 + 2][d] + bvd, Vred[seg * 4 + 3][d] + bvd);
  }
}

// ---------------------------------------------------------------------------
// Fused flash attention: 1024 threads = 16 waves = 4 KV-groups x 4 q-subtiles.
// Wave (g, wl): q rows [wl*16, wl*16+16), kv range [g*256, (g+1)*256).
// Swapped operands (S^T = K*Q, H^T = V^T*P) -> lane-local online softmax.
// Partials combined through LDS at the end (no global round-trip).
// Block mapping: both blocks of batch b land on XCD b&7 -> K/V L2-resident.
// ---------------------------------------------------------------------------
__global__ __launch_bounds__(1024, 4) void attn_kernel(
    const short* __restrict__ Q, const short* __restrict__ K,
    const short* __restrict__ VT, float* __restrict__ Out)
{
  __shared__ short Plds[16][16][72];
  __shared__ float HL[4][64][68];
  __shared__ float2 ML[4][64];

  const int t = threadIdx.x, lane = t & 63, w = t >> 6;
  const int g = w >> 2, wl = w & 3;
  const int fr = lane & 15, fg = lane >> 4;
  // XCD-aware mapping (round-robin model: block i -> XCD i&7)
  const int xcd = blockIdx.x & 7;
  const int idx = blockIdx.x >> 3;        // 0..31
  const int b   = xcd + ((idx & 1) << 3);
  const int q0  = (idx >> 1) * 64;
  const int qrow = q0 + wl * 16;

  const short* Qb  = Q  + (size_t)b * LEN * HD;
  const short* Kb  = K  + ((size_t)b * LEN + g * KVQ) * HD;
  const short* VTb = VT + (size_t)b * HD * LEN + g * KVQ;

  s16x8 qa0 = *reinterpret_cast<const s16x8*>(Qb + (size_t)(qrow + fr) * HD + fg * 8);
  s16x8 qa1 = *reinterpret_cast<const s16x8*>(Qb + (size_t)(qrow + fr) * HD + 32 + fg * 8);

  fx4 hacc[4];
#pragma unroll
  for (int c = 0; c < 4; ++c) hacc[c] = fx4{0.f, 0.f, 0.f, 0.f};
  float mrun = -1e30f, lsum = 0.f;
  const float SC = 0.125f * 1.44269504088896340736f;  // 1/sqrt(64) * log2(e)

  s16x8 kA[4][2], kB[4][2];
#pragma unroll
  for (int s = 0; s < 4; ++s) {
    const short* kp = Kb + (size_t)(s * 16 + fr) * HD + fg * 8;
    kA[s][0] = *reinterpret_cast<const s16x8*>(kp);
    kA[s][1] = *reinterpret_cast<const s16x8*>(kp + 32);
  }

#pragma unroll
  for (int it = 0; it < KVQ / 64; ++it) {
    const int kv0 = it * 64;
    s16x8 vb[4][2];
#pragma unroll
    for (int c = 0; c < 4; ++c) {
      const short* vp = VTb + (size_t)(c * 16 + fr) * LEN + kv0 + fg * 8;
      vb[c][0] = *reinterpret_cast<const s16x8*>(vp);
      vb[c][1] = *reinterpret_cast<const s16x8*>(vp + 32);
    }
    s16x8 (*kc)[2] = (it & 1) ? kB : kA;
    s16x8 (*kn)[2] = (it & 1) ? kA : kB;
    fx4 sacc[4];
#pragma unroll
    for (int s = 0; s < 4; ++s) {
      fx4 z = fx4{0.f, 0.f, 0.f, 0.f};
      z = mfma16(kc[s][0], qa0, z);
      sacc[s] = mfma16(kc[s][1], qa1, z);
    }
    if (it + 1 < KVQ / 64) {
#pragma unroll
      for (int s = 0; s < 4; ++s) {
        const short* kp = Kb + (size_t)(kv0 + 64 + s * 16 + fr) * HD + fg * 8;
        kn[s][0] = *reinterpret_cast<const s16x8*>(kp);
        kn[s][1] = *reinterpret_cast<const s16x8*>(kp + 32);
      }
    }
    float xs[4][4];
    float xm = -1e30f;
#pragma unroll
    for (int s = 0; s < 4; ++s)
#pragma unroll
      for (int r = 0; r < 4; ++r) {
        xs[s][r] = sacc[s][r] * SC;
        xm = fmaxf(xm, xs[s][r]);
      }
    xm = fmaxf(xm, __shfl_xor(xm, 16, 64));
    xm = fmaxf(xm, __shfl_xor(xm, 32, 64));
    const float mn = fmaxf(mrun, xm);
    const float corr = __builtin_amdgcn_exp2f(mrun - mn);
    mrun = mn;
    float ps = 0.f;
#pragma unroll
    for (int s = 0; s < 4; ++s) {
      float p[4];
#pragma unroll
      for (int r = 0; r < 4; ++r) {
        p[r] = __builtin_amdgcn_exp2f(xs[s][r] - mn);
        ps += p[r];
      }
      *reinterpret_cast<s16x4*>(&Plds[w][fr][s * 16 + fg * 4]) =
          cvt4(p[0], p[1], p[2], p[3]);
    }
    ps += __shfl_xor(ps, 16, 64);
    ps += __shfl_xor(ps, 32, 64);
    lsum = lsum * corr + ps;
    __builtin_amdgcn_wave_barrier();
    s16x8 pa0 = *reinterpret_cast<const s16x8*>(&Plds[w][fr][fg * 8]);
    s16x8 pa1 = *reinterpret_cast<const s16x8*>(&Plds[w][fr][32 + fg * 8]);
#pragma unroll
    for (int c = 0; c < 4; ++c) {
      fx4 h = hacc[c];
#pragma unroll
      for (int r = 0; r < 4; ++r) h[r] *= corr;
      h = mfma16(vb[c][0], pa0, h);
      hacc[c] = mfma16(vb[c][1], pa1, h);
    }
  }
  // partials -> LDS
#pragma unroll
  for (int c = 0; c < 4; ++c)
    *reinterpret_cast<fx4*>(&HL[g][wl * 16 + fr][c * 16 + fg * 4]) = hacc[c];
  if (fg == 0) ML[g][wl * 16 + fr] = make_float2(mrun, lsum);
  __syncthreads();
  // combine 4 KV-groups per q-row; 1024 threads x 4 outputs
  const int row = t >> 4, d0 = (t & 15) * 4;
  const float2 s0 = ML[0][row], s1 = ML[1][row], s2 = ML[2][row], s3 = ML[3][row];
  const float mm = fmaxf(fmaxf(s0.x, s1.x), fmaxf(s2.x, s3.x));
  const float w0 = __builtin_amdgcn_exp2f(s0.x - mm);
  const float w1 = __builtin_amdgcn_exp2f(s1.x - mm);
  const float w2 = __builtin_amdgcn_exp2f(s2.x - mm);
  const float w3 = __builtin_amdgcn_exp2f(s3.x - mm);
  const float inv = 1.0f / (s0.y * w0 + s1.y * w1 + s2.y * w2 + s3.y * w3);
  fx4 h0 = *reinterpret_cast<const fx4*>(&HL[0][row][d0]);
  fx4 h1 = *reinterpret_cast<const fx4*>(&HL[1][row][d0]);
  fx4 h2 = *reinterpret_cast<const fx4*>(&HL[2][row][d0]);
  fx4 h3 = *reinterpret_cast<const fx4*>(&HL[3][row][d0]);
  fx4 o;
#pragma unroll
  for (int r = 0; r < 4; ++r)
    o[r] = (h0[r] * w0 + h1[r] * w1 + h2[r] * w2 + h3[r] * w3) * inv;
  *reinterpret_cast<fx4*>(Out + ((size_t)b * LEN + q0 + row) * HD + d0) = o;
}

extern "C" void kernel_launch(void* const* d_in, const int* in_sizes, int n_in,
                              void* d_out, int out_size, void* d_ws, size_t ws_size,
                              hipStream_t stream) {
  const float* dec = (const float*)d_in[0];
  const float* enc = (const float*)d_in[1];
  const float* Wq  = (const float*)d_in[2];
  const float* bq  = (const float*)d_in[3];
  const float* Wk  = (const float*)d_in[4];
  const float* bk  = (const float*)d_in[5];
  const float* Wv  = (const float*)d_in[6];
  const float* bv  = (const float*)d_in[7];
  float* out = (float*)d_out;

  short* qws  = (short*)d_ws;                        // [16384,64] bf16
  short* kws  = qws + (size_t)M_TOT * HD;            // [16384,64] bf16
  short* vtws = kws + (size_t)M_TOT * HD;            // [16,64,1024] bf16

  proj_q_kernel<<<M_TOT / 64, 1024, 0, stream>>>(dec, Wq, bq, qws);
  proj_kv_kernel<<<M_TOT / 64, 1024, 0, stream>>>(enc, Wk, bk, Wv, bv, kws, vtws);
  attn_kernel<<<NB * (LEN / 64), 1024, 0, stream>>>(qws, kws, vtws, out);
}

// Round 5
// 44.018 us; speedup vs baseline: 1.5762x; 1.5762x over previous
//
#include <hip/hip_runtime.h>
#include <hip/hip_bf16.h>

typedef __attribute__((ext_vector_type(8))) short s16x8;
typedef __attribute__((ext_vector_type(4))) short s16x4;
typedef __attribute__((ext_vector_type(4))) float fx4;

#define DEVINL __device__ __forceinline__

constexpr int EMBED = 768;
constexpr int HD    = 64;
constexpr int NB    = 16;
constexpr int LEN   = 1024;
constexpr int M_TOT = NB * LEN;  // 16384
constexpr int KVQ   = LEN / 4;   // 256 kv per group in fused attn

// fp32 -> bf16 RNE via v_cvt_pk_bf16_f32 (2 elems/inst).
DEVINL unsigned pk2(float lo, float hi) {
  __hip_bfloat162 h = __float22bfloat162_rn(float2{lo, hi});
  union { __hip_bfloat162 h; unsigned u; } c; c.h = h;
  return c.u;
}
DEVINL s16x8 cvt8(fx4 a, fx4 b) {
  union { unsigned u[4]; s16x8 v; } r;
  r.u[0] = pk2(a[0], a[1]); r.u[1] = pk2(a[2], a[3]);
  r.u[2] = pk2(b[0], b[1]); r.u[3] = pk2(b[2], b[3]);
  return r.v;
}
DEVINL s16x4 cvt4(float a0, float a1, float a2, float a3) {
  union { unsigned u[2]; s16x4 v; } r;
  r.u[0] = pk2(a0, a1); r.u[1] = pk2(a2, a3);
  return r.v;
}

DEVINL fx4 mfma16(s16x8 a, s16x8 b, fx4 c) {
  return __builtin_amdgcn_mfma_f32_16x16x32_bf16(a, b, c, 0, 0, 0);
}

// ---------------------------------------------------------------------------
// proj_q: Y[m][d] = bf16( X[m][:] @ W[d][:] + b[d] ). Block = 1024 threads =
// 16 waves = 4 K-groups x 4 waves; partials summed through LDS.
// ---------------------------------------------------------------------------
__global__ __launch_bounds__(1024, 4) void proj_q_kernel(
    const float* __restrict__ X, const float* __restrict__ W,
    const float* __restrict__ bias, short* __restrict__ Y)
{
  __shared__ short Xs[4][64][40];
  __shared__ short Ws[4][64][40];
  __shared__ float Red[64][68];
  const int t = threadIdx.x, wv = t >> 6, lane = t & 63;
  const int g = wv >> 2, wl = wv & 3, u = t & 255;
  const int fr = lane & 15, fg = lane >> 4;
  const int m0 = blockIdx.x * 64;
  const int srow = u >> 2, scol = (u & 3) * 8;

  const float* xrow = X + (size_t)(m0 + srow) * EMBED + g * 192 + scol;
  const float* wrow = W + (size_t)srow * EMBED + g * 192 + scol;

  fx4 acc[4];
#pragma unroll
  for (int c = 0; c < 4; ++c) acc[c] = fx4{0.f, 0.f, 0.f, 0.f};

  fx4 px0 = *reinterpret_cast<const fx4*>(xrow);
  fx4 px1 = *reinterpret_cast<const fx4*>(xrow + 4);
  fx4 pw0 = *reinterpret_cast<const fx4*>(wrow);
  fx4 pw1 = *reinterpret_cast<const fx4*>(wrow + 4);

#pragma unroll
  for (int s = 0; s < 6; ++s) {
    s16x8 xb = cvt8(px0, px1);
    s16x8 wb = cvt8(pw0, pw1);
    __syncthreads();  // previous step's fragment reads complete
    *reinterpret_cast<s16x8*>(&Xs[g][srow][scol]) = xb;
    *reinterpret_cast<s16x8*>(&Ws[g][srow][scol]) = wb;
    if (s < 5) {  // prefetch next step
      px0 = *reinterpret_cast<const fx4*>(xrow + (s + 1) * 32);
      px1 = *reinterpret_cast<const fx4*>(xrow + (s + 1) * 32 + 4);
      pw0 = *reinterpret_cast<const fx4*>(wrow + (s + 1) * 32);
      pw1 = *reinterpret_cast<const fx4*>(wrow + (s + 1) * 32 + 4);
    }
    __syncthreads();
    s16x8 xa = *reinterpret_cast<const s16x8*>(&Xs[g][wl * 16 + fr][fg * 8]);
#pragma unroll
    for (int c = 0; c < 4; ++c) {
      s16x8 wf = *reinterpret_cast<const s16x8*>(&Ws[g][c * 16 + fr][fg * 8]);
      acc[c] = mfma16(wf, xa, acc[c]);  // D[d][m]: d=c*16+fg*4+r, m=wl*16+fr
    }
  }
  for (int gg = 0; gg < 4; ++gg) {
    if (g == gg) {
#pragma unroll
      for (int c = 0; c < 4; ++c) {
        float* p = &Red[wl * 16 + fr][c * 16 + fg * 4];
        if (gg == 0) {
          *reinterpret_cast<fx4*>(p) = acc[c];
        } else {
          fx4 v = *reinterpret_cast<fx4*>(p);
#pragma unroll
          for (int r = 0; r < 4; ++r) v[r] += acc[c][r];
          *reinterpret_cast<fx4*>(p) = v;
        }
      }
    }
    __syncthreads();
  }
  const int row = t >> 4, d0 = (t & 15) * 4;
  fx4 v = *reinterpret_cast<const fx4*>(&Red[row][d0]);
  fx4 bv = *reinterpret_cast<const fx4*>(bias + d0);
  *reinterpret_cast<s16x4*>(Y + (size_t)(m0 + row) * HD + d0) =
      cvt4(v[0] + bv[0], v[1] + bv[1], v[2] + bv[2], v[3] + bv[3]);
}

// ---------------------------------------------------------------------------
// proj_kv: enc -> K [b,kv,64] bf16 and V^T [b,64,kv] bf16. Same structure.
// ---------------------------------------------------------------------------
__global__ __launch_bounds__(1024, 4) void proj_kv_kernel(
    const float* __restrict__ X,
    const float* __restrict__ Wk, const float* __restrict__ bk,
    const float* __restrict__ Wv, const float* __restrict__ bv,
    short* __restrict__ Kout, short* __restrict__ VT)
{
  __shared__ short Xs[4][64][40];
  __shared__ short Wks[4][64][40];
  __shared__ short Wvs[4][64][40];
  __shared__ float Kred[64][68];
  __shared__ float Vred[64][68];
  const int t = threadIdx.x, wv = t >> 6, lane = t & 63;
  const int g = wv >> 2, wl = wv & 3, u = t & 255;
  const int fr = lane & 15, fg = lane >> 4;
  const int m0 = blockIdx.x * 64;
  const int srow = u >> 2, scol = (u & 3) * 8;

  const float* xrow  = X  + (size_t)(m0 + srow) * EMBED + g * 192 + scol;
  const float* wkrow = Wk + (size_t)srow * EMBED + g * 192 + scol;
  const float* wvrow = Wv + (size_t)srow * EMBED + g * 192 + scol;

  fx4 kacc[4], vacc[4];
#pragma unroll
  for (int c = 0; c < 4; ++c) {
    kacc[c] = fx4{0.f, 0.f, 0.f, 0.f};
    vacc[c] = fx4{0.f, 0.f, 0.f, 0.f};
  }

  fx4 px0 = *reinterpret_cast<const fx4*>(xrow);
  fx4 px1 = *reinterpret_cast<const fx4*>(xrow + 4);
  fx4 pk0 = *reinterpret_cast<const fx4*>(wkrow);
  fx4 pk1 = *reinterpret_cast<const fx4*>(wkrow + 4);
  fx4 pv0 = *reinterpret_cast<const fx4*>(wvrow);
  fx4 pv1 = *reinterpret_cast<const fx4*>(wvrow + 4);

#pragma unroll
  for (int s = 0; s < 6; ++s) {
    s16x8 xb = cvt8(px0, px1);
    s16x8 kb = cvt8(pk0, pk1);
    s16x8 vb = cvt8(pv0, pv1);
    __syncthreads();
    *reinterpret_cast<s16x8*>(&Xs[g][srow][scol])  = xb;
    *reinterpret_cast<s16x8*>(&Wks[g][srow][scol]) = kb;
    *reinterpret_cast<s16x8*>(&Wvs[g][srow][scol]) = vb;
    if (s < 5) {
      px0 = *reinterpret_cast<const fx4*>(xrow + (s + 1) * 32);
      px1 = *reinterpret_cast<const fx4*>(xrow + (s + 1) * 32 + 4);
      pk0 = *reinterpret_cast<const fx4*>(wkrow + (s + 1) * 32);
      pk1 = *reinterpret_cast<const fx4*>(wkrow + (s + 1) * 32 + 4);
      pv0 = *reinterpret_cast<const fx4*>(wvrow + (s + 1) * 32);
      pv1 = *reinterpret_cast<const fx4*>(wvrow + (s + 1) * 32 + 4);
    }
    __syncthreads();
    s16x8 xa = *reinterpret_cast<const s16x8*>(&Xs[g][wl * 16 + fr][fg * 8]);
#pragma unroll
    for (int c = 0; c < 4; ++c) {
      s16x8 wkf = *reinterpret_cast<const s16x8*>(&Wks[g][c * 16 + fr][fg * 8]);
      s16x8 wvf = *reinterpret_cast<const s16x8*>(&Wvs[g][c * 16 + fr][fg * 8]);
      kacc[c] = mfma16(wkf, xa, kacc[c]);
      vacc[c] = mfma16(wvf, xa, vacc[c]);
    }
  }
  for (int gg = 0; gg < 4; ++gg) {
    if (g == gg) {
#pragma unroll
      for (int c = 0; c < 4; ++c) {
        float* pk = &Kred[wl * 16 + fr][c * 16 + fg * 4];
        float* pv = &Vred[wl * 16 + fr][c * 16 + fg * 4];
        if (gg == 0) {
          *reinterpret_cast<fx4*>(pk) = kacc[c];
          *reinterpret_cast<fx4*>(pv) = vacc[c];
        } else {
          fx4 a = *reinterpret_cast<fx4*>(pk);
          fx4 b = *reinterpret_cast<fx4*>(pv);
#pragma unroll
          for (int r = 0; r < 4; ++r) { a[r] += kacc[c][r]; b[r] += vacc[c][r]; }
          *reinterpret_cast<fx4*>(pk) = a;
          *reinterpret_cast<fx4*>(pv) = b;
        }
      }
    }
    __syncthreads();
  }
  {
    const int row = t >> 4, d0 = (t & 15) * 4;
    fx4 v = *reinterpret_cast<const fx4*>(&Kred[row][d0]);
    fx4 b4 = *reinterpret_cast<const fx4*>(bk + d0);
    *reinterpret_cast<s16x4*>(Kout + (size_t)(m0 + row) * HD + d0) =
        cvt4(v[0] + b4[0], v[1] + b4[1], v[2] + b4[2], v[3] + b4[3]);
  }
  {
    const int d = t >> 4, seg = t & 15;
    const int bidx = m0 >> 10;             // 64 | 1024: no batch straddle
    const int kvpos = (m0 & 1023) + seg * 4;
    const float bvd = bv[d];
    *reinterpret_cast<s16x4*>(VT + ((size_t)(bidx * HD + d)) * LEN + kvpos) =
        cvt4(Vred[seg * 4][d] + bvd, Vred[seg * 4 + 1][d] + bvd,
             Vred[seg * 4 + 2][d] + bvd, Vred[seg * 4 + 3][d] + bvd);
  }
}

// ---------------------------------------------------------------------------
// Fused flash attention. 1024 threads = 16 waves = 4 KV-groups x 4 q-waves.
// Wave (g,wl): q rows [wl*16,+16), kv range [g*256,+256). K/V tiles staged in
// LDS per group (shared by its 4 waves; padded rows -> 2-way aliasing only),
// fragments ds_read just before MFMA -> no big register arrays, no spill.
// T14 split: next tile's global loads issue into regs before compute,
// ds_write after the post-compute barrier. Partials combined via LDS overlay.
// ---------------------------------------------------------------------------
__global__ __launch_bounds__(1024, 4) void attn_kernel(
    const short* __restrict__ Q, const short* __restrict__ K,
    const short* __restrict__ VT, float* __restrict__ Out)
{
  __shared__ __align__(16) char smem[110592];
  // Loop-phase layout:
  //   Kls [4][64][72] shorts @ 0       (36864 B)
  //   Vls [4][64][72] shorts @ 36864   (36864 B)
  //   Plds[16][16][72] shorts @ 73728  (36864 B)
  // Combine-phase overlay (after loop, staging dead):
  //   HL [4][64][68] float @ 0 (69632 B), ML [4][64] float2 @ 69632 (2048 B)
  short (*Kls)[64][72]  = reinterpret_cast<short(*)[64][72]>(smem);
  short (*Vls)[64][72]  = reinterpret_cast<short(*)[64][72]>(smem + 36864);
  short (*Plds)[16][72] = reinterpret_cast<short(*)[16][72]>(smem + 73728);
  float (*HL)[64][68]   = reinterpret_cast<float(*)[64][68]>(smem);
  float2 (*ML)[64]      = reinterpret_cast<float2(*)[64]>(smem + 69632);

  const int t = threadIdx.x, lane = t & 63, w = t >> 6;
  const int g = w >> 2, wl = w & 3;
  const int fr = lane & 15, fg = lane >> 4;
  // XCD-aware mapping (round-robin model: block i -> XCD i&7)
  const int xcd = blockIdx.x & 7;
  const int idx = blockIdx.x >> 3;        // 0..31
  const int b   = xcd + ((idx & 1) << 3);
  const int q0  = (idx >> 1) * 64;
  const int qrow = q0 + wl * 16;

  const short* Qb  = Q  + (size_t)b * LEN * HD;
  const short* Kb  = K  + ((size_t)b * LEN + g * KVQ) * HD;
  const short* VTb = VT + (size_t)b * HD * LEN + g * KVQ;

  s16x8 qa0 = *reinterpret_cast<const s16x8*>(Qb + (size_t)(qrow + fr) * HD + fg * 8);
  s16x8 qa1 = *reinterpret_cast<const s16x8*>(Qb + (size_t)(qrow + fr) * HD + 32 + fg * 8);

  fx4 hacc[4];
#pragma unroll
  for (int c = 0; c < 4; ++c) hacc[c] = fx4{0.f, 0.f, 0.f, 0.f};
  float mrun = -1e30f, lsum = 0.f;
  const float SC = 0.125f * 1.44269504088896340736f;  // 1/sqrt(64) * log2(e)

  // cooperative staging indices (256 threads per group; u = group-local id)
  const int u = t & 255;
  const int srow = u >> 2;          // 0..63
  const int sch  = (u & 3) * 16;    // short col offset: 0,16,32,48 (32B/lane)

  // prologue: load tile 0 -> regs -> LDS
  s16x8 pk0 = *reinterpret_cast<const s16x8*>(Kb + (size_t)srow * HD + sch);
  s16x8 pk1 = *reinterpret_cast<const s16x8*>(Kb + (size_t)srow * HD + sch + 8);
  s16x8 pv0 = *reinterpret_cast<const s16x8*>(VTb + (size_t)srow * LEN + sch);
  s16x8 pv1 = *reinterpret_cast<const s16x8*>(VTb + (size_t)srow * LEN + sch + 8);
  *reinterpret_cast<s16x8*>(&Kls[g][srow][sch])     = pk0;
  *reinterpret_cast<s16x8*>(&Kls[g][srow][sch + 8]) = pk1;
  *reinterpret_cast<s16x8*>(&Vls[g][srow][sch])     = pv0;
  *reinterpret_cast<s16x8*>(&Vls[g][srow][sch + 8]) = pv1;
  __syncthreads();

#pragma unroll
  for (int it = 0; it < KVQ / 64; ++it) {
    // T14: issue next tile's global loads before compute
    if (it + 1 < KVQ / 64) {
      const int nk = (it + 1) * 64;
      pk0 = *reinterpret_cast<const s16x8*>(Kb + (size_t)(nk + srow) * HD + sch);
      pk1 = *reinterpret_cast<const s16x8*>(Kb + (size_t)(nk + srow) * HD + sch + 8);
      pv0 = *reinterpret_cast<const s16x8*>(VTb + (size_t)srow * LEN + nk + sch);
      pv1 = *reinterpret_cast<const s16x8*>(VTb + (size_t)srow * LEN + nk + sch + 8);
    }
    // S^T = K * Q from LDS; lane: q = fr, kv = s*16 + fg*4 + r
    fx4 sacc[4];
#pragma unroll
    for (int s = 0; s < 4; ++s) {
      s16x8 kf0 = *reinterpret_cast<const s16x8*>(&Kls[g][s * 16 + fr][fg * 8]);
      s16x8 kf1 = *reinterpret_cast<const s16x8*>(&Kls[g][s * 16 + fr][32 + fg * 8]);
      fx4 z = fx4{0.f, 0.f, 0.f, 0.f};
      z = mfma16(kf0, qa0, z);
      sacc[s] = mfma16(kf1, qa1, z);
    }
    // per-lane online softmax for q-row fr
    float xs[4][4];
    float xm = -1e30f;
#pragma unroll
    for (int s = 0; s < 4; ++s)
#pragma unroll
      for (int r = 0; r < 4; ++r) {
        xs[s][r] = sacc[s][r] * SC;
        xm = fmaxf(xm, xs[s][r]);
      }
    xm = fmaxf(xm, __shfl_xor(xm, 16, 64));
    xm = fmaxf(xm, __shfl_xor(xm, 32, 64));
    const float mn = fmaxf(mrun, xm);
    const float corr = __builtin_amdgcn_exp2f(mrun - mn);
    mrun = mn;
    float ps = 0.f;
#pragma unroll
    for (int s = 0; s < 4; ++s) {
      float p[4];
#pragma unroll
      for (int r = 0; r < 4; ++r) {
        p[r] = __builtin_amdgcn_exp2f(xs[s][r] - mn);
        ps += p[r];
      }
      *reinterpret_cast<s16x4*>(&Plds[w][fr][s * 16 + fg * 4]) =
          cvt4(p[0], p[1], p[2], p[3]);
    }
    ps += __shfl_xor(ps, 16, 64);
    ps += __shfl_xor(ps, 32, 64);
    lsum = lsum * corr + ps;
    __builtin_amdgcn_wave_barrier();
    s16x8 pa0 = *reinterpret_cast<const s16x8*>(&Plds[w][fr][fg * 8]);
    s16x8 pa1 = *reinterpret_cast<const s16x8*>(&Plds[w][fr][32 + fg * 8]);
    // H^T += V^T * P from LDS; rescale lane-local
#pragma unroll
    for (int c = 0; c < 4; ++c) {
      s16x8 vf0 = *reinterpret_cast<const s16x8*>(&Vls[g][c * 16 + fr][fg * 8]);
      s16x8 vf1 = *reinterpret_cast<const s16x8*>(&Vls[g][c * 16 + fr][32 + fg * 8]);
      fx4 h = hacc[c];
#pragma unroll
      for (int r = 0; r < 4; ++r) h[r] *= corr;
      h = mfma16(vf0, pa0, h);
      hacc[c] = mfma16(vf1, pa1, h);
    }
    __syncthreads();  // all waves done reading tile it
    if (it + 1 < KVQ / 64) {
      *reinterpret_cast<s16x8*>(&Kls[g][srow][sch])     = pk0;
      *reinterpret_cast<s16x8*>(&Kls[g][srow][sch + 8]) = pk1;
      *reinterpret_cast<s16x8*>(&Vls[g][srow][sch])     = pv0;
      *reinterpret_cast<s16x8*>(&Vls[g][srow][sch + 8]) = pv1;
    }
    __syncthreads();  // tile it+1 visible
  }
  // partials -> LDS overlay (staging region is dead now; barrier above done)
#pragma unroll
  for (int c = 0; c < 4; ++c)
    *reinterpret_cast<fx4*>(&HL[g][wl * 16 + fr][c * 16 + fg * 4]) = hacc[c];
  if (fg == 0) ML[g][wl * 16 + fr] = make_float2(mrun, lsum);
  __syncthreads();
  // combine 4 KV-groups per q-row; 1024 threads x 4 outputs
  const int row = t >> 4, d0 = (t & 15) * 4;
  const float2 s0 = ML[0][row], s1 = ML[1][row], s2 = ML[2][row], s3 = ML[3][row];
  const float mm = fmaxf(fmaxf(s0.x, s1.x), fmaxf(s2.x, s3.x));
  const float w0 = __builtin_amdgcn_exp2f(s0.x - mm);
  const float w1 = __builtin_amdgcn_exp2f(s1.x - mm);
  const float w2 = __builtin_amdgcn_exp2f(s2.x - mm);
  const float w3 = __builtin_amdgcn_exp2f(s3.x - mm);
  const float inv = 1.0f / (s0.y * w0 + s1.y * w1 + s2.y * w2 + s3.y * w3);
  fx4 h0 = *reinterpret_cast<const fx4*>(&HL[0][row][d0]);
  fx4 h1 = *reinterpret_cast<const fx4*>(&HL[1][row][d0]);
  fx4 h2 = *reinterpret_cast<const fx4*>(&HL[2][row][d0]);
  fx4 h3 = *reinterpret_cast<const fx4*>(&HL[3][row][d0]);
  fx4 o;
#pragma unroll
  for (int r = 0; r < 4; ++r)
    o[r] = (h0[r] * w0 + h1[r] * w1 + h2[r] * w2 + h3[r] * w3) * inv;
  *reinterpret_cast<fx4*>(Out + ((size_t)b * LEN + q0 + row) * HD + d0) = o;
}

extern "C" void kernel_launch(void* const* d_in, const int* in_sizes, int n_in,
                              void* d_out, int out_size, void* d_ws, size_t ws_size,
                              hipStream_t stream) {
  const float* dec = (const float*)d_in[0];
  const float* enc = (const float*)d_in[1];
  const float* Wq  = (const float*)d_in[2];
  const float* bq  = (const float*)d_in[3];
  const float* Wk  = (const float*)d_in[4];
  const float* bk  = (const float*)d_in[5];
  const float* Wv  = (const float*)d_in[6];
  const float* bv  = (const float*)d_in[7];
  float* out = (float*)d_out;

  short* qws  = (short*)d_ws;                        // [16384,64] bf16
  short* kws  = qws + (size_t)M_TOT * HD;            // [16384,64] bf16
  short* vtws = kws + (size_t)M_TOT * HD;            // [16,64,1024] bf16

  proj_q_kernel<<<M_TOT / 64, 1024, 0, stream>>>(dec, Wq, bq, qws);
  proj_kv_kernel<<<M_TOT / 64, 1024, 0, stream>>>(enc, Wk, bk, Wv, bv, kws, vtws);
  attn_kernel<<<NB * (LEN / 64), 1024, 0, stream>>>(qws, kws, vtws, out);
}